// Round 23
// baseline (48.726 us; speedup 1.0000x reference)
//
#include <hip/hip_runtime.h>
#include <hip/hip_bf16.h>

// GAT fused forward loss.
// R23: R22's fusion retried WITHOUT LDS (R22's 64KB static __shared__ was
// allocated for all 1152 blocks -> madj occupancy collapsed 8->2 blocks/CU).
// k_front: blocks 0..1023 pack sampled adj rows -> 2MB bitmask (R21 body,
// full occupancy); blocks 1024..1151 run the Wh MFMA GEMM with B-frags built
// per-iteration from global W in registers (32 scalar f32 loads, 64B
// coalesced per 16-lane group; W L2-hot). All blocks co-resident -> wh
// overlaps under the madj stream. k_mattn (mask-fed) + k_loss unchanged.
// Mask layout: u16 per 16 consecutive j, bit = j&15; consumer tile t, lane
// kg: byte ((t&1)*4+kg) of u64 #(t>>1).

#define NN 8192
#define FTDIM 512
#define CDIM 64
#define NTRAIN 1024
#define LOG2E 1.44269504088896f

typedef __attribute__((ext_vector_type(8))) short short8;
typedef __attribute__((ext_vector_type(4))) float f32x4;
typedef __attribute__((ext_vector_type(4))) int i32x4;

static __device__ __forceinline__ unsigned short f2bf(float x) {
    return __bfloat16_as_ushort(__float2bfloat16(x));
}
static __device__ __forceinline__ float bf2f(unsigned short u) {
    return __uint_as_float((unsigned)u << 16);
}

// ---------------------------------------------------------------------------
// Kernel F (fused front, NO LDS): grid 1152 x 256.
// blocks 0..1023 (madj): wave = half-row of (l,ks), i = idxt[ks]; 4 iters of
//   lane-contiguous 4x i32x4 (1KB/instr) -> u16 mask -> coalesced store.
// blocks 1024..1151 (wh): wave wv owns rows ((bid-1024)*4+wv)*16..+16.
//   Per k-iter: A-frag = contiguous feat bf16 (4-deep prefetch); B-frags
//   built from global W: lane loads W[(it*4+kg)*8+e][nt*16+r] (8 e x 4 nt;
//   each instr = 4x 64B segments, L2-hot) -> cvt bf16. 4 MFMAs.
//   Epilogue: Vt2[jblk][c][e] + tables sQ=(2^s',2^(0.2s'),2^(-s'));
//   dE1=2^d', dE2=2^(0.2d').
// ---------------------------------------------------------------------------
__global__ __launch_bounds__(256) void k_front(
    const int* __restrict__ adj1, const int* __restrict__ adj2,
    const int* __restrict__ idxt, const float* __restrict__ W,
    const float* __restrict__ feat, const float* __restrict__ av,
    unsigned short* __restrict__ maskB, unsigned short* __restrict__ Vt2,
    float4* __restrict__ sQ, float* __restrict__ dE1, float* __restrict__ dE2,
    float* __restrict__ out)
{
    const int tid = threadIdx.x;
    const int bid = blockIdx.x;
    const int lane = tid & 63;

    if (bid < 1024) {
        // ---------------- madj: pack sampled adj rows ----------------
        if (bid == 0 && tid == 0) out[0] = 0.f;

        const int w2   = bid * 4 + (tid >> 6);   // 0..4095
        const int half = w2 & 1;
        const int row  = w2 >> 1;                // l*1024 + ks
        const int l    = row >> 10;
        const int ks   = row & 1023;
        const int i    = idxt[ks];

        const int* __restrict__ arow =
            (l ? adj2 : adj1) + (size_t)i * NN + half * 4096;
        unsigned short* __restrict__ mrow =
            maskB + (size_t)row * 512 + half * 256;

#pragma unroll
        for (int u = 0; u < 4; ++u) {
            const int lb = u * 1024 + lane * 16;
            const i32x4 a0 = *(const i32x4*)(arow + lb);
            const i32x4 a1 = *(const i32x4*)(arow + lb + 4);
            const i32x4 a2 = *(const i32x4*)(arow + lb + 8);
            const i32x4 a3 = *(const i32x4*)(arow + lb + 12);
            unsigned m = 0;
#pragma unroll
            for (int e = 0; e < 4; ++e) {
                m |= (a0[e] != 0 ? 1u : 0u) << e;
                m |= (a1[e] != 0 ? 1u : 0u) << (4 + e);
                m |= (a2[e] != 0 ? 1u : 0u) << (8 + e);
                m |= (a3[e] != 0 ? 1u : 0u) << (12 + e);
            }
            mrow[u * 64 + lane] = (unsigned short)m;
        }
        return;
    }

    // ---------------- wh: Wh = feat @ W via MFMA (B from global W) --------
    const int wv = tid >> 6;
    const int r  = lane & 15;
    const int kg = lane >> 4;
    const int row0 = ((bid - 1024) * 4 + wv) * 16;

    const float* __restrict__ fp = feat + (size_t)(row0 + r) * FTDIM + kg * 8;

    f32x4 fa[4], fb[4];
#pragma unroll
    for (int d = 0; d < 4; ++d) {
        fa[d] = *(const f32x4*)(fp + d * 32);
        fb[d] = *(const f32x4*)(fp + d * 32 + 4);
    }

    f32x4 acc0 = {0.f, 0.f, 0.f, 0.f};
    f32x4 acc1 = acc0, acc2 = acc0, acc3 = acc0;

    for (int it = 0; it < 16; ++it) {
        const int slot = it & 3;
        const f32x4 a0 = fa[slot], a1 = fb[slot];
        if (it + 4 < 16) {
            fa[slot] = *(const f32x4*)(fp + (it + 4) * 32);
            fb[slot] = *(const f32x4*)(fp + (it + 4) * 32 + 4);
        }

        // B-frags from global W (L2-hot): wf[nt][e] = W[(it*4+kg)*8+e][nt*16+r]
        const float* __restrict__ wp = W + ((size_t)(it * 4 + kg) * 8) * CDIM + r;
        float wf[4][8];
#pragma unroll
        for (int e = 0; e < 8; ++e) {
#pragma unroll
            for (int nt = 0; nt < 4; ++nt)
                wf[nt][e] = wp[e * CDIM + nt * 16];
        }

        short8 af;
#pragma unroll
        for (int e = 0; e < 4; ++e) {
            af[e]     = (short)f2bf(a0[e]);
            af[4 + e] = (short)f2bf(a1[e]);
        }
        short8 b0, b1, b2, b3;
#pragma unroll
        for (int e = 0; e < 8; ++e) {
            b0[e] = (short)f2bf(wf[0][e]);
            b1[e] = (short)f2bf(wf[1][e]);
            b2[e] = (short)f2bf(wf[2][e]);
            b3[e] = (short)f2bf(wf[3][e]);
        }

        acc0 = __builtin_amdgcn_mfma_f32_16x16x32_bf16(af, b0, acc0, 0, 0, 0);
        acc1 = __builtin_amdgcn_mfma_f32_16x16x32_bf16(af, b1, acc1, 0, 0, 0);
        acc2 = __builtin_amdgcn_mfma_f32_16x16x32_bf16(af, b2, acc2, 0, 0, 0);
        acc3 = __builtin_amdgcn_mfma_f32_16x16x32_bf16(af, b3, acc3, 0, 0, 0);
    }

    const size_t jblk = (size_t)(row0 >> 3) + (kg >> 1);
    const int e0 = (kg & 1) * 4;
#pragma unroll
    for (int nt = 0; nt < 4; ++nt) {
        const f32x4 a = (nt == 0) ? acc0 : (nt == 1) ? acc1 : (nt == 2) ? acc2 : acc3;
        ushort4 v4;
        v4.x = f2bf(a[0]); v4.y = f2bf(a[1]); v4.z = f2bf(a[2]); v4.w = f2bf(a[3]);
        *(ushort4*)(Vt2 + jblk * 512 + (size_t)(nt * 16 + r) * 8 + e0) = v4;
    }

    float a1v[4], a2v[4];
#pragma unroll
    for (int nt = 0; nt < 4; ++nt) {
        a1v[nt] = av[nt * 16 + r];
        a2v[nt] = av[CDIM + nt * 16 + r];
    }
#pragma unroll
    for (int q = 0; q < 4; ++q) {
        float s_ = acc0[q] * a1v[0] + acc1[q] * a1v[1]
                 + acc2[q] * a1v[2] + acc3[q] * a1v[3];
        float d_ = acc0[q] * a2v[0] + acc1[q] * a2v[1]
                 + acc2[q] * a2v[2] + acc3[q] * a2v[3];
#pragma unroll
        for (int off = 8; off; off >>= 1) {
            s_ += __shfl_xor(s_, off);
            d_ += __shfl_xor(d_, off);
        }
        if (r == 0) {
            const int i = row0 + kg * 4 + q;
            const float sp = s_ * LOG2E, dp_ = d_ * LOG2E;
            sQ[i] = make_float4(__builtin_amdgcn_exp2f(sp),
                                __builtin_amdgcn_exp2f(0.2f * sp),
                                __builtin_amdgcn_exp2f(-sp), 0.f);
            dE1[i] = __builtin_amdgcn_exp2f(dp_);
            dE2[i] = __builtin_amdgcn_exp2f(0.2f * dp_);
        }
    }
}

// ---------------------------------------------------------------------------
// Kernel M (R21): main loop with u64 mask loads + byte extracts. sc-major
// mapping (block's 4 waves share the Vt2/dE window), bf16 partials.
// ---------------------------------------------------------------------------
struct TileS {
    f32x4 a0, a1, b0, b1;
    short8 v0, v1, v2, v3;
};

template<int SCL>
__global__ __launch_bounds__(256, 4) void k_mattn(
    const unsigned short* __restrict__ maskB,
    const unsigned short* __restrict__ Vt2, const float4* __restrict__ sQ,
    const float* __restrict__ dE1, const float* __restrict__ dE2,
    const int* __restrict__ idxt,
    unsigned short* __restrict__ numPartB, float* __restrict__ zPart)
{
    constexpr int NT = (NN >> SCL) >> 5;
    const int lane = threadIdx.x & 63;
    const int w = (int)((blockIdx.x * blockDim.x + threadIdx.x) >> 6);
    const int l   = w >> (6 + SCL);
    const int rem = w & ((64 << SCL) - 1);
    const int sc  = rem >> 6;
    const int sb  = rem & 63;

    const int r  = lane & 15;
    const int kg = lane >> 4;

    const int ks = sb * 16 + r;
    const int i = idxt[ks];
    const float4 sq = sQ[i];
    const float E1 = sq.x, E2 = sq.y, th = sq.z;

    const int j0 = sc * (NN >> SCL);
    const float* __restrict__ d1p = dE1 + j0 + kg * 8;
    const float* __restrict__ d2p = dE2 + j0 + kg * 8;
    const unsigned short* __restrict__ vbase =
        Vt2 + (((size_t)j0 >> 3) << 9) + ((size_t)kg << 9) + (r << 3);

    const unsigned long long* __restrict__ mptr =
        (const unsigned long long*)((const char*)maskB
            + (size_t)((l << 10) + ks) * 1024 + (j0 >> 3));
    unsigned long long mw[NT / 2];
#pragma unroll
    for (int ww = 0; ww < NT / 2; ++ww) mw[ww] = mptr[ww];

    unsigned mbits[NT];
#pragma unroll
    for (int t = 0; t < NT; ++t)
        mbits[t] = (unsigned)(mw[t >> 1] >> (((t & 1) * 4 + kg) * 8)) & 0xffu;

    short8 bOnes;
#pragma unroll
    for (int e = 0; e < 8; ++e) bOnes[e] = (short)0x3F80;

    f32x4 acc0 = {0.f, 0.f, 0.f, 0.f};
    f32x4 acc1 = acc0, acc2 = acc0, acc3 = acc0, accz = acc0;

    TileS tA, tB;

#define LOADT(T, JT) do { const int _jr = (JT) * 32;                           \
    T.a0 = *(const f32x4*)(d1p + _jr);                                         \
    T.a1 = *(const f32x4*)(d1p + _jr + 4);                                     \
    T.b0 = *(const f32x4*)(d2p + _jr);                                         \
    T.b1 = *(const f32x4*)(d2p + _jr + 4);                                     \
    const unsigned short* _vp = vbase + ((size_t)(JT) << 11);                  \
    T.v0 = *(const short8*)(_vp);                                              \
    T.v1 = *(const short8*)(_vp + 128);                                        \
    T.v2 = *(const short8*)(_vp + 256);                                        \
    T.v3 = *(const short8*)(_vp + 384);                                        \
} while (0)

#define COMPT(T, JT) do {                                                      \
    const unsigned _mb = mbits[JT];                                            \
    short8 af;                                                                 \
    _Pragma("unroll")                                                          \
    for (int e = 0; e < 8; ++e) {                                              \
        const float e1 = (e < 4) ? T.a0[e & 3] : T.a1[e & 3];                  \
        const float e2 = (e < 4) ? T.b0[e & 3] : T.b1[e & 3];                  \
        const bool pos = e1 > th;                                              \
        float p = (pos ? e1 : e2) * (pos ? E1 : E2);                           \
        p = ((_mb >> e) & 1u) ? p : 0.f;                                       \
        af[e] = (short)f2bf(p);                                                \
    }                                                                          \
    acc0 = __builtin_amdgcn_mfma_f32_16x16x32_bf16(af, T.v0, acc0, 0, 0, 0);   \
    acc1 = __builtin_amdgcn_mfma_f32_16x16x32_bf16(af, T.v1, acc1, 0, 0, 0);   \
    acc2 = __builtin_amdgcn_mfma_f32_16x16x32_bf16(af, T.v2, acc2, 0, 0, 0);   \
    acc3 = __builtin_amdgcn_mfma_f32_16x16x32_bf16(af, T.v3, acc3, 0, 0, 0);   \
    accz = __builtin_amdgcn_mfma_f32_16x16x32_bf16(af, bOnes, accz, 0, 0, 0);  \
} while (0)

    LOADT(tA, 0);
#pragma unroll
    for (int jt = 0; jt < NT - 2; jt += 2) {
        LOADT(tB, jt + 1);
        COMPT(tA, jt);
        LOADT(tA, jt + 2);
        COMPT(tB, jt + 1);
    }
    LOADT(tB, NT - 1);
    COMPT(tA, NT - 2);
    COMPT(tB, NT - 1);
#undef LOADT
#undef COMPT

    constexpr int SC = 1 << SCL;
#pragma unroll
    for (int q = 0; q < 4; ++q) {
        const int kss = sb * 16 + kg * 4 + q;
        const size_t slot = ((size_t)kss * 2 + l) * SC + sc;
        unsigned short* op = numPartB + slot * CDIM + r;
        op[0]  = f2bf(acc0[q]);
        op[16] = f2bf(acc1[q]);
        op[32] = f2bf(acc2[q]);
        op[48] = f2bf(acc3[q]);
        if (r == 0) zPart[slot] = accz[q];
    }
}

// ---------------------------------------------------------------------------
// Kernel C: per-sample loss + fused mean (atomicAdd into out, zeroed by
// k_front). Bit-exact pass since R19.
// ---------------------------------------------------------------------------
__global__ __launch_bounds__(256) void k_loss(
    const unsigned short* __restrict__ numPartB, const float* __restrict__ zPart,
    const int* __restrict__ labels, const int* __restrict__ idxt,
    float* __restrict__ out, const int scLog2)
{
    __shared__ float lsum[4];
    const int tid = threadIdx.x;
    const int lane = tid & 63;
    const int wv = tid >> 6;
    const int k = (int)((blockIdx.x * blockDim.x + tid) >> 6);
    const int SC = 1 << scLog2;

    float logit = 0.f;
#pragma unroll
    for (int l = 0; l < 2; ++l) {
        const size_t base = ((size_t)k * 2 + l) * SC;
        float ns = 0.f;
#pragma unroll 16
        for (int s = 0; s < SC; ++s)
            ns += bf2f(numPartB[(base + s) * CDIM + lane]);
        float zs = (lane < SC) ? zPart[base + lane] : 0.f;
#pragma unroll
        for (int off = 32; off; off >>= 1) zs += __shfl_xor(zs, off);
        logit += fmaxf(ns / zs, 0.f);   // relu(elu(x)) == relu(x)
    }
    logit *= 0.5f;

    float m = logit;
#pragma unroll
    for (int off = 32; off; off >>= 1) m = fmaxf(m, __shfl_xor(m, off));
    float ex = __expf(logit - m);
    float sum = ex;
#pragma unroll
    for (int off = 32; off; off >>= 1) sum += __shfl_xor(sum, off);
    const float logp = logit - m - __logf(sum);

    const int y = labels[idxt[k]];
    const float t = __shfl(logp, y);
    if (lane == 0) lsum[wv] = -t;
    __syncthreads();
    if (tid == 0)
        atomicAdd(out, (lsum[0] + lsum[1] + lsum[2] + lsum[3]) * (1.f / 1024.f));
}

// ---------------------------------------------------------------------------
extern "C" void kernel_launch(void* const* d_in, const int* in_sizes, int n_in,
                              void* d_out, int out_size, void* d_ws, size_t ws_size,
                              hipStream_t stream)
{
    const float* feat   = (const float*)d_in[0];
    const float* W      = (const float*)d_in[1];
    const float* av     = (const float*)d_in[2];
    const int*   adj1   = (const int*)d_in[3];
    const int*   adj2   = (const int*)d_in[4];
    const int*   labels = (const int*)d_in[5];
    const int*   idxt   = (const int*)d_in[6];

    // head: Vt2 1MB | sQ 128KB | dE1 32KB | dE2 32KB | maskB 2MB
    const size_t MASKB = 2ull * NTRAIN * (NN / 8);         // 2 MB
    const size_t HEAD  = (1u << 20) + (192u << 10) + MASKB;

    auto needed = [&](int scl) -> size_t {
        const size_t SC = (size_t)1 << scl;
        return HEAD + 2 * SC * NTRAIN * CDIM * sizeof(unsigned short)
                    + 2 * SC * NTRAIN * sizeof(float);
    };
    const int scLog2 = (ws_size >= needed(5)) ? 5 : 4;
    const int SC = 1 << scLog2;

    char* ws = (char*)d_ws;
    unsigned short* Vt2 = (unsigned short*)ws;                       // 1 MB
    float4* sQ  = (float4*)(ws + (1u << 20));                        // 128 KB
    float*  dE1 = (float*)(ws + (1u << 20) + (128u << 10));          // 32 KB
    float*  dE2 = (float*)(ws + (1u << 20) + (160u << 10));          // 32 KB
    unsigned short* maskB = (unsigned short*)(ws + (1u << 20) + (192u << 10));
    unsigned short* numPartB = (unsigned short*)(ws + HEAD);
    float*  zPart  = (float*)((char*)numPartB
                              + 2ull * SC * NTRAIN * CDIM * sizeof(unsigned short));

    hipLaunchKernelGGL(k_front, dim3(1152), dim3(256), 0, stream,
                       adj1, adj2, idxt, W, feat, av,
                       maskB, Vt2, sQ, dE1, dE2, (float*)d_out);
    if (scLog2 == 5)
        hipLaunchKernelGGL((k_mattn<5>), dim3(32 * 32), dim3(256), 0, stream,
                           maskB, Vt2, sQ, dE1, dE2, idxt, numPartB, zPart);
    else
        hipLaunchKernelGGL((k_mattn<4>), dim3(32 * 16), dim3(256), 0, stream,
                           maskB, Vt2, sQ, dE1, dE2, idxt, numPartB, zPart);
    hipLaunchKernelGGL(k_loss, dim3(NTRAIN / 4), dim3(256), 0, stream,
                       numPartB, zPart, labels, idxt, (float*)d_out, scLog2);
}

// Round 25
// 42.338 us; speedup vs baseline: 1.1509x; 1.1509x over previous
//
#include <hip/hip_runtime.h>
#include <hip/hip_bf16.h>

// GAT fused forward loss.
// R25 = R21 champion (42.1us, absmax 0.0), reverted verbatim after three
// failed overlap attempts (R22 LDS-occupancy collapse, R23 hetero-grid tail,
// R24 cooperative-launch failure). Structure:
//  k_madj: pack ~960 sampled adj rows (only h_all[idx_train] is live) into a
//    2MB bitmask with sequential lane-contiguous dwordx4 reads; also builds
//    Wt2 (bf16 B-operand) and zeros d_out.
//  k_wh: Wh = feat @ W via MFMA 16x16x32 (A = contiguous feat bf16, 4-deep
//    prefetch; B = short8 from L2-hot Wt2); epilogue writes Vt2 + factored-exp
//    tables sQ=(2^s',2^(0.2s'),2^(-s')), dE1=2^d', dE2=2^(0.2d').
//  k_mattn: wave = (layer, 16-sample block, j-chunk); mask u64 loads + byte
//    extracts; p = bit ? (e1>th ? E1*e1 : E2*e2) : 0 (exact exp(lrelu(s+d)),
//    no transcendental); 4 MFMAs numerator + 1 vs ones = Z; sc-major block
//    mapping (4 waves share Vt2/dE window); bf16 partials.
//  k_loss: per-sample log-softmax NLL + fused mean via one atomicAdd/block.
// Mask layout: u16 per 16 consecutive j, bit = j&15; consumer tile t, lane
// kg: byte ((t&1)*4+kg) of u64 #(t>>1).

#define NN 8192
#define FTDIM 512
#define CDIM 64
#define NTRAIN 1024
#define LOG2E 1.44269504088896f

typedef __attribute__((ext_vector_type(8))) short short8;
typedef __attribute__((ext_vector_type(4))) float f32x4;
typedef __attribute__((ext_vector_type(4))) int i32x4;

static __device__ __forceinline__ unsigned short f2bf(float x) {
    return __bfloat16_as_ushort(__float2bfloat16(x));
}
static __device__ __forceinline__ float bf2f(unsigned short u) {
    return __uint_as_float((unsigned)u << 16);
}

// ---------------------------------------------------------------------------
// Kernel J: pack sampled adj rows -> maskB (2MB) + build Wt2 + zero d_out.
// 1024 blocks x 256. Wave w2 = half-row of (l,ks): row i = idxt[ks].
// Per iter (4): lane reads 16 consecutive ints (4x i32x4, instruction-
// contiguous 1KB/64-lane) -> u16 (bit = j&15) -> coalesced store.
// Blocks 0..15 additionally build Wt2[kblk][c][e] = bf16(W[kblk*8+e][c]).
// ---------------------------------------------------------------------------
__global__ __launch_bounds__(256) void k_madj(
    const int* __restrict__ adj1, const int* __restrict__ adj2,
    const int* __restrict__ idxt, const float* __restrict__ W,
    unsigned short* __restrict__ Wt2, unsigned short* __restrict__ maskB,
    float* __restrict__ out)
{
    const int tid = threadIdx.x;

    if (blockIdx.x < 16) {
        const int idx = blockIdx.x * 256 + tid;    // 0..4095
        const int kblk = idx >> 6, c = idx & 63;
        short8 v;
#pragma unroll
        for (int e = 0; e < 8; ++e)
            v[e] = (short)f2bf(W[(kblk * 8 + e) * CDIM + c]);
        *(short8*)(Wt2 + (size_t)idx * 8) = v;
        if (blockIdx.x == 0 && tid == 0) out[0] = 0.f;
    }

    const int lane = tid & 63;
    const int w2   = blockIdx.x * 4 + (tid >> 6);  // 0..4095
    const int half = w2 & 1;
    const int row  = w2 >> 1;                      // l*1024 + ks
    const int l    = row >> 10;
    const int ks   = row & 1023;
    const int i    = idxt[ks];

    const int* __restrict__ arow = (l ? adj2 : adj1) + (size_t)i * NN + half * 4096;
    unsigned short* __restrict__ mrow = maskB + (size_t)row * 512 + half * 256;

#pragma unroll
    for (int u = 0; u < 4; ++u) {
        const int lb = u * 1024 + lane * 16;
        const i32x4 a0 = *(const i32x4*)(arow + lb);
        const i32x4 a1 = *(const i32x4*)(arow + lb + 4);
        const i32x4 a2 = *(const i32x4*)(arow + lb + 8);
        const i32x4 a3 = *(const i32x4*)(arow + lb + 12);
        unsigned m = 0;
#pragma unroll
        for (int e = 0; e < 4; ++e) {
            m |= (a0[e] != 0 ? 1u : 0u) << e;
            m |= (a1[e] != 0 ? 1u : 0u) << (4 + e);
            m |= (a2[e] != 0 ? 1u : 0u) << (8 + e);
            m |= (a3[e] != 0 ? 1u : 0u) << (12 + e);
        }
        mrow[u * 64 + lane] = (unsigned short)m;
    }
}

// ---------------------------------------------------------------------------
// Kernel A: Wh = feat @ W via MFMA 16x16x32. One wave per 16 rows; 512
// blocks. A-frag = contiguous feat bf16 (4-deep prefetch); B-frags = short8
// from L2-hot Wt2. Epilogue: Vt2 + factored-exp tables.
// ---------------------------------------------------------------------------
__global__ __launch_bounds__(64) void k_wh(
    const float* __restrict__ feat, const unsigned short* __restrict__ Wt2,
    const float* __restrict__ av, unsigned short* __restrict__ Vt2,
    float4* __restrict__ sQ, float* __restrict__ dE1, float* __restrict__ dE2)
{
    const int lane = threadIdx.x;
    const int r  = lane & 15;
    const int kg = lane >> 4;
    const int row0 = blockIdx.x * 16;

    const float* __restrict__ fp = feat + (size_t)(row0 + r) * FTDIM + kg * 8;

    f32x4 fa[4], fb[4];
#pragma unroll
    for (int d = 0; d < 4; ++d) {
        fa[d] = *(const f32x4*)(fp + d * 32);
        fb[d] = *(const f32x4*)(fp + d * 32 + 4);
    }

    f32x4 acc0 = {0.f, 0.f, 0.f, 0.f};
    f32x4 acc1 = acc0, acc2 = acc0, acc3 = acc0;

    for (int it = 0; it < 16; ++it) {
        const int slot = it & 3;
        const f32x4 a0 = fa[slot], a1 = fb[slot];
        if (it + 4 < 16) {
            fa[slot] = *(const f32x4*)(fp + (it + 4) * 32);
            fb[slot] = *(const f32x4*)(fp + (it + 4) * 32 + 4);
        }

        short8 af;
#pragma unroll
        for (int e = 0; e < 4; ++e) {
            af[e]     = (short)f2bf(a0[e]);
            af[4 + e] = (short)f2bf(a1[e]);
        }

        const unsigned short* bp = Wt2 + ((size_t)(it * 4 + kg)) * 512 + (r << 3);
        const short8 b0 = *(const short8*)(bp);
        const short8 b1 = *(const short8*)(bp + 128);
        const short8 b2 = *(const short8*)(bp + 256);
        const short8 b3 = *(const short8*)(bp + 384);

        acc0 = __builtin_amdgcn_mfma_f32_16x16x32_bf16(af, b0, acc0, 0, 0, 0);
        acc1 = __builtin_amdgcn_mfma_f32_16x16x32_bf16(af, b1, acc1, 0, 0, 0);
        acc2 = __builtin_amdgcn_mfma_f32_16x16x32_bf16(af, b2, acc2, 0, 0, 0);
        acc3 = __builtin_amdgcn_mfma_f32_16x16x32_bf16(af, b3, acc3, 0, 0, 0);
    }

    const size_t jblk = (size_t)(row0 >> 3) + (kg >> 1);
    const int e0 = (kg & 1) * 4;
#pragma unroll
    for (int nt = 0; nt < 4; ++nt) {
        const f32x4 a = (nt == 0) ? acc0 : (nt == 1) ? acc1 : (nt == 2) ? acc2 : acc3;
        ushort4 v4;
        v4.x = f2bf(a[0]); v4.y = f2bf(a[1]); v4.z = f2bf(a[2]); v4.w = f2bf(a[3]);
        *(ushort4*)(Vt2 + jblk * 512 + (size_t)(nt * 16 + r) * 8 + e0) = v4;
    }

    float a1v[4], a2v[4];
#pragma unroll
    for (int nt = 0; nt < 4; ++nt) {
        a1v[nt] = av[nt * 16 + r];
        a2v[nt] = av[CDIM + nt * 16 + r];
    }
#pragma unroll
    for (int q = 0; q < 4; ++q) {
        float s_ = acc0[q] * a1v[0] + acc1[q] * a1v[1]
                 + acc2[q] * a1v[2] + acc3[q] * a1v[3];
        float d_ = acc0[q] * a2v[0] + acc1[q] * a2v[1]
                 + acc2[q] * a2v[2] + acc3[q] * a2v[3];
#pragma unroll
        for (int off = 8; off; off >>= 1) {
            s_ += __shfl_xor(s_, off);
            d_ += __shfl_xor(d_, off);
        }
        if (r == 0) {
            const int i = row0 + kg * 4 + q;
            const float sp = s_ * LOG2E, dp_ = d_ * LOG2E;
            sQ[i] = make_float4(__builtin_amdgcn_exp2f(sp),
                                __builtin_amdgcn_exp2f(0.2f * sp),
                                __builtin_amdgcn_exp2f(-sp), 0.f);
            dE1[i] = __builtin_amdgcn_exp2f(dp_);
            dE2[i] = __builtin_amdgcn_exp2f(0.2f * dp_);
        }
    }
}

// ---------------------------------------------------------------------------
// Kernel M: main loop with u64 mask loads + byte extracts. sc-major mapping
// (block's 4 waves share the Vt2/dE window), bf16 partials.
// ---------------------------------------------------------------------------
struct TileS {
    f32x4 a0, a1, b0, b1;
    short8 v0, v1, v2, v3;
};

template<int SCL>
__global__ __launch_bounds__(256, 4) void k_mattn(
    const unsigned short* __restrict__ maskB,
    const unsigned short* __restrict__ Vt2, const float4* __restrict__ sQ,
    const float* __restrict__ dE1, const float* __restrict__ dE2,
    const int* __restrict__ idxt,
    unsigned short* __restrict__ numPartB, float* __restrict__ zPart)
{
    constexpr int NT = (NN >> SCL) >> 5;
    const int lane = threadIdx.x & 63;
    const int w = (int)((blockIdx.x * blockDim.x + threadIdx.x) >> 6);
    const int l   = w >> (6 + SCL);
    const int rem = w & ((64 << SCL) - 1);
    const int sc  = rem >> 6;
    const int sb  = rem & 63;

    const int r  = lane & 15;
    const int kg = lane >> 4;

    const int ks = sb * 16 + r;
    const int i = idxt[ks];
    const float4 sq = sQ[i];
    const float E1 = sq.x, E2 = sq.y, th = sq.z;

    const int j0 = sc * (NN >> SCL);
    const float* __restrict__ d1p = dE1 + j0 + kg * 8;
    const float* __restrict__ d2p = dE2 + j0 + kg * 8;
    const unsigned short* __restrict__ vbase =
        Vt2 + (((size_t)j0 >> 3) << 9) + ((size_t)kg << 9) + (r << 3);

    const unsigned long long* __restrict__ mptr =
        (const unsigned long long*)((const char*)maskB
            + (size_t)((l << 10) + ks) * 1024 + (j0 >> 3));
    unsigned long long mw[NT / 2];
#pragma unroll
    for (int ww = 0; ww < NT / 2; ++ww) mw[ww] = mptr[ww];

    unsigned mbits[NT];
#pragma unroll
    for (int t = 0; t < NT; ++t)
        mbits[t] = (unsigned)(mw[t >> 1] >> (((t & 1) * 4 + kg) * 8)) & 0xffu;

    short8 bOnes;
#pragma unroll
    for (int e = 0; e < 8; ++e) bOnes[e] = (short)0x3F80;

    f32x4 acc0 = {0.f, 0.f, 0.f, 0.f};
    f32x4 acc1 = acc0, acc2 = acc0, acc3 = acc0, accz = acc0;

    TileS tA, tB;

#define LOADT(T, JT) do { const int _jr = (JT) * 32;                           \
    T.a0 = *(const f32x4*)(d1p + _jr);                                         \
    T.a1 = *(const f32x4*)(d1p + _jr + 4);                                     \
    T.b0 = *(const f32x4*)(d2p + _jr);                                         \
    T.b1 = *(const f32x4*)(d2p + _jr + 4);                                     \
    const unsigned short* _vp = vbase + ((size_t)(JT) << 11);                  \
    T.v0 = *(const short8*)(_vp);                                              \
    T.v1 = *(const short8*)(_vp + 128);                                        \
    T.v2 = *(const short8*)(_vp + 256);                                        \
    T.v3 = *(const short8*)(_vp + 384);                                        \
} while (0)

#define COMPT(T, JT) do {                                                      \
    const unsigned _mb = mbits[JT];                                            \
    short8 af;                                                                 \
    _Pragma("unroll")                                                          \
    for (int e = 0; e < 8; ++e) {                                              \
        const float e1 = (e < 4) ? T.a0[e & 3] : T.a1[e & 3];                  \
        const float e2 = (e < 4) ? T.b0[e & 3] : T.b1[e & 3];                  \
        const bool pos = e1 > th;                                              \
        float p = (pos ? e1 : e2) * (pos ? E1 : E2);                           \
        p = ((_mb >> e) & 1u) ? p : 0.f;                                       \
        af[e] = (short)f2bf(p);                                                \
    }                                                                          \
    acc0 = __builtin_amdgcn_mfma_f32_16x16x32_bf16(af, T.v0, acc0, 0, 0, 0);   \
    acc1 = __builtin_amdgcn_mfma_f32_16x16x32_bf16(af, T.v1, acc1, 0, 0, 0);   \
    acc2 = __builtin_amdgcn_mfma_f32_16x16x32_bf16(af, T.v2, acc2, 0, 0, 0);   \
    acc3 = __builtin_amdgcn_mfma_f32_16x16x32_bf16(af, T.v3, acc3, 0, 0, 0);   \
    accz = __builtin_amdgcn_mfma_f32_16x16x32_bf16(af, bOnes, accz, 0, 0, 0);  \
} while (0)

    LOADT(tA, 0);
#pragma unroll
    for (int jt = 0; jt < NT - 2; jt += 2) {
        LOADT(tB, jt + 1);
        COMPT(tA, jt);
        LOADT(tA, jt + 2);
        COMPT(tB, jt + 1);
    }
    LOADT(tB, NT - 1);
    COMPT(tA, NT - 2);
    COMPT(tB, NT - 1);
#undef LOADT
#undef COMPT

    constexpr int SC = 1 << SCL;
#pragma unroll
    for (int q = 0; q < 4; ++q) {
        const int kss = sb * 16 + kg * 4 + q;
        const size_t slot = ((size_t)kss * 2 + l) * SC + sc;
        unsigned short* op = numPartB + slot * CDIM + r;
        op[0]  = f2bf(acc0[q]);
        op[16] = f2bf(acc1[q]);
        op[32] = f2bf(acc2[q]);
        op[48] = f2bf(acc3[q]);
        if (r == 0) zPart[slot] = accz[q];
    }
}

// ---------------------------------------------------------------------------
// Kernel C: per-sample loss + fused mean (atomicAdd into out, zeroed by
// k_madj). Bit-exact pass since R19.
// ---------------------------------------------------------------------------
__global__ __launch_bounds__(256) void k_loss(
    const unsigned short* __restrict__ numPartB, const float* __restrict__ zPart,
    const int* __restrict__ labels, const int* __restrict__ idxt,
    float* __restrict__ out, const int scLog2)
{
    __shared__ float lsum[4];
    const int tid = threadIdx.x;
    const int lane = tid & 63;
    const int wv = tid >> 6;
    const int k = (int)((blockIdx.x * blockDim.x + tid) >> 6);
    const int SC = 1 << scLog2;

    float logit = 0.f;
#pragma unroll
    for (int l = 0; l < 2; ++l) {
        const size_t base = ((size_t)k * 2 + l) * SC;
        float ns = 0.f;
#pragma unroll 16
        for (int s = 0; s < SC; ++s)
            ns += bf2f(numPartB[(base + s) * CDIM + lane]);
        float zs = (lane < SC) ? zPart[base + lane] : 0.f;
#pragma unroll
        for (int off = 32; off; off >>= 1) zs += __shfl_xor(zs, off);
        logit += fmaxf(ns / zs, 0.f);   // relu(elu(x)) == relu(x)
    }
    logit *= 0.5f;

    float m = logit;
#pragma unroll
    for (int off = 32; off; off >>= 1) m = fmaxf(m, __shfl_xor(m, off));
    float ex = __expf(logit - m);
    float sum = ex;
#pragma unroll
    for (int off = 32; off; off >>= 1) sum += __shfl_xor(sum, off);
    const float logp = logit - m - __logf(sum);

    const int y = labels[idxt[k]];
    const float t = __shfl(logp, y);
    if (lane == 0) lsum[wv] = -t;
    __syncthreads();
    if (tid == 0)
        atomicAdd(out, (lsum[0] + lsum[1] + lsum[2] + lsum[3]) * (1.f / 1024.f));
}

// ---------------------------------------------------------------------------
extern "C" void kernel_launch(void* const* d_in, const int* in_sizes, int n_in,
                              void* d_out, int out_size, void* d_ws, size_t ws_size,
                              hipStream_t stream)
{
    const float* feat   = (const float*)d_in[0];
    const float* W      = (const float*)d_in[1];
    const float* av     = (const float*)d_in[2];
    const int*   adj1   = (const int*)d_in[3];
    const int*   adj2   = (const int*)d_in[4];
    const int*   labels = (const int*)d_in[5];
    const int*   idxt   = (const int*)d_in[6];

    // head: Vt2 1MB | Wt2 64KB | sQ 128KB | dE1 32KB | dE2 32KB | maskB 2MB
    const size_t MASKB = 2ull * NTRAIN * (NN / 8);         // 2 MB
    const size_t HEAD  = (1u << 20) + (256u << 10) + MASKB;

    auto needed = [&](int scl) -> size_t {
        const size_t SC = (size_t)1 << scl;
        return HEAD + 2 * SC * NTRAIN * CDIM * sizeof(unsigned short)
                    + 2 * SC * NTRAIN * sizeof(float);
    };
    const int scLog2 = (ws_size >= needed(5)) ? 5 : 4;
    const int SC = 1 << scLog2;

    char* ws = (char*)d_ws;
    unsigned short* Vt2 = (unsigned short*)ws;                       // 1 MB
    unsigned short* Wt2 = (unsigned short*)(ws + (1u << 20));        // 64 KB
    float4* sQ  = (float4*)(ws + (1u << 20) + (64u << 10));          // 128 KB
    float*  dE1 = (float*)(ws + (1u << 20) + (192u << 10));          // 32 KB
    float*  dE2 = (float*)(ws + (1u << 20) + (224u << 10));          // 32 KB
    unsigned short* maskB = (unsigned short*)(ws + (1u << 20) + (256u << 10));
    unsigned short* numPartB = (unsigned short*)(ws + HEAD);
    float*  zPart  = (float*)((char*)numPartB
                              + 2ull * SC * NTRAIN * CDIM * sizeof(unsigned short));

    hipLaunchKernelGGL(k_madj, dim3(1024), dim3(256), 0, stream,
                       adj1, adj2, idxt, W, Wt2, maskB, (float*)d_out);
    hipLaunchKernelGGL(k_wh, dim3(512), dim3(64), 0, stream,
                       feat, Wt2, av, Vt2, sQ, dE1, dE2);
    if (scLog2 == 5)
        hipLaunchKernelGGL((k_mattn<5>), dim3(32 * 32), dim3(256), 0, stream,
                           maskB, Vt2, sQ, dE1, dE2, idxt, numPartB, zPart);
    else
        hipLaunchKernelGGL((k_mattn<4>), dim3(32 * 16), dim3(256), 0, stream,
                           maskB, Vt2, sQ, dE1, dE2, idxt, numPartB, zPart);
    hipLaunchKernelGGL(k_loss, dim3(NTRAIN / 4), dim3(256), 0, stream,
                       numPartB, zPart, labels, idxt, (float*)d_out, scLog2);
}